// Round 11
// baseline (571.799 us; speedup 1.0000x reference)
//
#include <hip/hip_runtime.h>

// y[b, i] = sum v * x[b, j] + biases[i]
// 320k edges, each a dense 4x4 block at (4r, 4c); values row-major per edge.
// Round 11: per-XCD queues (real XCC_ID) x 64-batch windows (2/XCD) x 4
// column tiles looped inside the block. Live xh slice per XCD = 1.28 MB
// (<4MB L2). Register acc persists across tiles; full-wave 512B gathers;
// steal only after own queue drains. Prepass = r10 virtual-row CSR.

typedef _Float16 h2_t __attribute__((ext_vector_type(2)));
typedef float f4_t __attribute__((ext_vector_type(4)));

__device__ __forceinline__ h2_t as_h2(unsigned u) {
  union { unsigned u; h2_t h; } v; v.u = u; return v.h;
}

__device__ __forceinline__ float fdot2(h2_t a, h2_t b, float c) {
#if __has_builtin(__builtin_amdgcn_fdot2)
  return __builtin_amdgcn_fdot2(a, b, c, false);
#else
  return c + (float)a.x * (float)b.x + (float)a.y * (float)b.y;
#endif
}

__device__ __forceinline__ int get_xcd() {
  unsigned x;
  asm volatile("s_getreg_b32 %0, hwreg(HW_REG_XCC_ID)" : "=s"(x));
  return (int)(x & 7);
}

// ---- fused pack + hist (virtual rows = row*4 + col-tile) ----
__global__ void pack_hist_kernel(const float* __restrict__ x, uint2* __restrict__ xh,
                                 const int* __restrict__ indices, int* __restrict__ cnt,
                                 int2* __restrict__ rc, int batch, int size, int E,
                                 int npx, int npack, int ts) {
  __shared__ float tile[64][65];
  int bid = blockIdx.x;
  if (bid < npack) {
    int bx = bid % npx, by = bid / npx;
    int c0 = bx * 64;
    int b0 = by * 64;
    int tx = threadIdx.x & 63, ty = threadIdx.x >> 6;
#pragma unroll
    for (int k = 0; k < 64; k += 4) {
      int b = b0 + ty + k, c = c0 + tx;
      if (b < batch && c < size) tile[ty + k][tx] = x[(size_t)b * size + c];
    }
    __syncthreads();
#pragma unroll
    for (int it = 0; it < 4; ++it) {
      int idx = it * 256 + threadIdx.x;
      int cn_local = idx >> 6;
      int bl = idx & 63;
      int c_node = (c0 >> 2) + cn_local;
      int b = b0 + bl;
      if (b < batch && (c_node * 4 + 3) < size) {
        union { _Float16 h[4]; uint2 u; } cv;
        cv.h[0] = (_Float16)tile[bl][cn_local * 4 + 0];
        cv.h[1] = (_Float16)tile[bl][cn_local * 4 + 1];
        cv.h[2] = (_Float16)tile[bl][cn_local * 4 + 2];
        cv.h[3] = (_Float16)tile[bl][cn_local * 4 + 3];
        xh[(size_t)c_node * batch + b] = cv.u;
      }
    }
  } else {
    int e = (bid - npack) * 256 + threadIdx.x;
    if (e < E) {
      int2 ij = *(const int2*)(indices + (size_t)e * 32);
      int r = ij.x >> 2, c = ij.y >> 2;
      int t = (c >= ts) + (c >= 2 * ts) + (c >= 3 * ts);
      int vr = (r << 2) + t;
      rc[e] = make_int2(vr, c);
      atomicAdd(&cnt[vr], 1);
    }
  }
}

// ---- parallel scan over n_vr counts ----
__global__ void scan_reduce_kernel(const int* __restrict__ cnt, int* __restrict__ partial, int n) {
  __shared__ int sh[256];
  int i = blockIdx.x * 256 + threadIdx.x;
  sh[threadIdx.x] = (i < n) ? cnt[i] : 0;
  __syncthreads();
  for (int off = 128; off > 0; off >>= 1) {
    if (threadIdx.x < off) sh[threadIdx.x] += sh[threadIdx.x + off];
    __syncthreads();
  }
  if (threadIdx.x == 0) partial[blockIdx.x] = sh[0];
}

__global__ void scan_mid_kernel(const int* __restrict__ partial, int* __restrict__ offs, int nb) {
  __shared__ int sh[256];
  int t = threadIdx.x;
  sh[t] = (t < nb) ? partial[t] : 0;
  __syncthreads();
  for (int off = 1; off < 256; off <<= 1) {
    int add = (t >= off) ? sh[t - off] : 0;
    __syncthreads();
    sh[t] += add;
    __syncthreads();
  }
  if (t < nb) offs[t] = sh[t];  // inclusive
}

__global__ void scan_final_kernel(const int* __restrict__ cnt, const int* __restrict__ offs,
                                  int* __restrict__ row_start, int n) {
  __shared__ int sh[256];
  int blk = blockIdx.x;
  int i = blk * 256 + threadIdx.x;
  int v = (i < n) ? cnt[i] : 0;
  sh[threadIdx.x] = v;
  __syncthreads();
  for (int off = 1; off < 256; off <<= 1) {
    int add = (threadIdx.x >= off) ? sh[threadIdx.x - off] : 0;
    __syncthreads();
    sh[threadIdx.x] += add;
    __syncthreads();
  }
  int base = (blk == 0) ? 0 : offs[blk - 1];
  if (i < n) row_start[i + 1] = sh[threadIdx.x] + base;
  if (blk == 0 && threadIdx.x == 0) row_start[0] = 0;
}

__global__ void scan_kernel(const int* __restrict__ cnt, int* __restrict__ row_start, int n) {
  __shared__ int buf[1024];
  __shared__ int carry_s;
  int t = threadIdx.x;
  if (t == 0) { carry_s = 0; row_start[0] = 0; }
  __syncthreads();
  for (int base = 0; base < n; base += 1024) {
    int v = (base + t < n) ? cnt[base + t] : 0;
    buf[t] = v;
    __syncthreads();
    for (int off = 1; off < 1024; off <<= 1) {
      int add = (t >= off) ? buf[t - off] : 0;
      __syncthreads();
      buf[t] += add;
      __syncthreads();
    }
    if (base + t < n) row_start[base + t + 1] = buf[t] + carry_s;
    __syncthreads();
    if (t == 0) carry_s += buf[1023];
    __syncthreads();
  }
}

// ---- fused scatter + vals fp16 conversion (virtual-row CSR order) ----
__global__ void scatter_vals_kernel(const int2* __restrict__ rc, const int* __restrict__ row_start,
                                    int* __restrict__ cursor, const float* __restrict__ vals,
                                    int* __restrict__ col_sorted, _Float16* __restrict__ vals_h,
                                    int E) {
  int e = blockIdx.x * blockDim.x + threadIdx.x;
  if (e >= E) return;
  int2 v = rc[e];
  int pos = row_start[v.x] + atomicAdd(&cursor[v.x], 1);
  col_sorted[pos] = v.y;
  const float* src = vals + (size_t)e * 16;
  union { _Float16 h[8]; uint4 u; } w0, w1;
#pragma unroll
  for (int i = 0; i < 8; ++i) w0.h[i] = (_Float16)src[i];
#pragma unroll
  for (int i = 0; i < 8; ++i) w1.h[i] = (_Float16)src[8 + i];
  *(uint4*)(vals_h + (size_t)pos * 16) = w0.u;
  *(uint4*)(vals_h + (size_t)pos * 16 + 8) = w1.u;
}

// One edge, one batch element (X = 4 fp16).
__device__ __forceinline__ void edge_acc(const _Float16* __restrict__ vh, size_t p,
                                         uint2 xu, float* __restrict__ acc) {
  uint4 A = *(const uint4*)(vh + p * 16);
  uint4 C = *(const uint4*)(vh + p * 16 + 8);
  h2_t x01 = as_h2(xu.x), x23 = as_h2(xu.y);
  acc[0] = fdot2(as_h2(A.x), x01, acc[0]); acc[0] = fdot2(as_h2(A.y), x23, acc[0]);
  acc[1] = fdot2(as_h2(A.z), x01, acc[1]); acc[1] = fdot2(as_h2(A.w), x23, acc[1]);
  acc[2] = fdot2(as_h2(C.x), x01, acc[2]); acc[2] = fdot2(as_h2(C.y), x23, acc[2]);
  acc[3] = fdot2(as_h2(C.z), x01, acc[3]); acc[3] = fdot2(as_h2(C.w), x23, acc[3]);
}

// Queued spmm: 8 queues (one per XCD). Queue q owns windows {q*wpq .. q*wpq+wpq-1}
// (64-batch each). Task = (window_local, quadgroup); block loops 4 col-tiles
// INTERNALLY with persistent register accumulators. Steal after own drain.
__global__ __launch_bounds__(256) void spmm_kernel(
    const int* __restrict__ row_start4, const int* __restrict__ col_sorted,
    const _Float16* __restrict__ vals_h, const uint2* __restrict__ xh2,
    const float* __restrict__ biases, float* __restrict__ out,
    int n_nodes, int batch, int size,
    int* __restrict__ qcnt, int nq, int wpq, int nqg) {
  __shared__ float tile[64][68];
  __shared__ int task_s;
  int xcd = get_xcd() % nq;
  int wave = threadIdx.x >> 6;
  int lane = threadIdx.x & 63;
  int npq = wpq * nqg;

  for (int dq = 0; dq < nq; ++dq) {
    int q = (xcd + dq) % nq;
    while (true) {
      __syncthreads();
      if (threadIdx.x == 0) task_s = atomicAdd(&qcnt[q], 1);
      __syncthreads();
      int t = task_s;
      if (t >= npq) break;

      int wl = t / nqg;
      int qg = t - wl * nqg;
      int w = q * wpq + wl;
      int quad = qg * 4 + wave;
      bool qvalid = (quad * 4 < n_nodes);
      int b = w * 64 + lane;
      bool bvalid = (b < batch);
      const uint2* __restrict__ xb = xh2 + (bvalid ? b : batch - 1);

      float acc[4][4];
#pragma unroll
      for (int i = 0; i < 16; ++i) ((float*)acc)[i] = 0.f;

      if (qvalid) {
#pragma unroll
        for (int tt = 0; tt < 4; ++tt) {   // column tiles, in phase across blocks
#pragma unroll
          for (int rr = 0; rr < 4; ++rr) {
            int r = quad * 4 + rr;
            if (r >= n_nodes) continue;
            int vr = (r << 2) + tt;
            int s = __builtin_amdgcn_readfirstlane(row_start4[vr]);
            int e = __builtin_amdgcn_readfirstlane(row_start4[vr + 1]);
            float* a = acc[rr];
            int p = s;
            for (; p + 3 < e; p += 4) {
              int c0 = col_sorted[p];
              int c1 = col_sorted[p + 1];
              int c2 = col_sorted[p + 2];
              int c3 = col_sorted[p + 3];
              uint2 X0 = xb[(size_t)c0 * batch];
              uint2 X1 = xb[(size_t)c1 * batch];
              uint2 X2 = xb[(size_t)c2 * batch];
              uint2 X3 = xb[(size_t)c3 * batch];
              edge_acc(vals_h, (size_t)p,     X0, a);
              edge_acc(vals_h, (size_t)p + 1, X1, a);
              edge_acc(vals_h, (size_t)p + 2, X2, a);
              edge_acc(vals_h, (size_t)p + 3, X3, a);
            }
            for (; p < e; ++p) {
              uint2 X = xb[(size_t)col_sorted[p] * batch];
              edge_acc(vals_h, (size_t)p, X, a);
            }
          }
        }
      }

      // ---- epilogue: LDS transpose -> full-line nontemporal stores ----
      __syncthreads();
      if (qvalid && bvalid) {
#pragma unroll
        for (int rr = 0; rr < 4; ++rr) {
          int r = quad * 4 + rr;
          if (r < n_nodes) {
            float4 bias = *(const float4*)&biases[r << 2];
            float4 o = make_float4(acc[rr][0] + bias.x, acc[rr][1] + bias.y,
                                   acc[rr][2] + bias.z, acc[rr][3] + bias.w);
            *(float4*)&tile[lane][wave * 16 + rr * 4] = o;
          }
        }
      }
      __syncthreads();
#pragma unroll
      for (int it = 0; it < 4; ++it) {
        int idx = it * 256 + threadIdx.x;
        int bl = idx >> 4;   // 0..63 batch elem within window
        int f4 = idx & 15;   // 16B chunk of the 64-float row group
        int r = qg * 16 + f4;
        int bb = w * 64 + bl;
        if (r < n_nodes && bb < batch) {
          f4_t v = *(f4_t*)&tile[bl][f4 * 4];
          __builtin_nontemporal_store(v, (f4_t*)&out[(size_t)bb * size + (size_t)r * 4]);
        }
      }
    }
  }
}

// Fallback when ws can't hold xh: gather fp32 x directly, fp16 V (virtual-row CSR).
__global__ __launch_bounds__(256) void spmm_fb_kernel(
    const int* __restrict__ row_start4, const int* __restrict__ col_sorted,
    const _Float16* __restrict__ vals_h, const float* __restrict__ x,
    const float* __restrict__ biases, float* __restrict__ out,
    int n_nodes, int batch, int size) {
  int quad = blockIdx.x;
  int b = blockIdx.y * blockDim.x + threadIdx.x;
  if (b >= batch || quad * 4 >= n_nodes) return;
  float acc[4][4];
#pragma unroll
  for (int i = 0; i < 16; ++i) ((float*)acc)[i] = 0.f;
#pragma unroll
  for (int rr = 0; rr < 4; ++rr) {
    int r = quad * 4 + rr;
    if (r >= n_nodes) break;
    int s = row_start4[r << 2], e = row_start4[(r << 2) + 4];  // all 4 tiles
    for (int p = s; p < e; ++p) {
      int c = col_sorted[p];
      float4 xv = *(const float4*)&x[(size_t)b * size + (c << 2)];
      const _Float16* V = vals_h + (size_t)p * 16;
#pragma unroll
      for (int i = 0; i < 4; ++i) {
        acc[rr][i] += (float)V[i * 4 + 0] * xv.x + (float)V[i * 4 + 1] * xv.y +
                      (float)V[i * 4 + 2] * xv.z + (float)V[i * 4 + 3] * xv.w;
      }
    }
  }
#pragma unroll
  for (int rr = 0; rr < 4; ++rr) {
    int r = quad * 4 + rr;
    if (r >= n_nodes) break;
    float4 bias = *(const float4*)&biases[r << 2];
    float4 o = make_float4(acc[rr][0] + bias.x, acc[rr][1] + bias.y,
                           acc[rr][2] + bias.z, acc[rr][3] + bias.w);
    *(float4*)&out[(size_t)b * size + (r << 2)] = o;
  }
}

// Last-resort fallback (tiny ws)
__global__ void bias_init_kernel(float* __restrict__ out, const float* __restrict__ biases,
                                 int batch, int size) {
  size_t t = (size_t)blockIdx.x * blockDim.x + threadIdx.x;
  size_t total = (size_t)batch * size;
  if (t >= total) return;
  out[t] = biases[t % size];
}

__global__ void atomic_spmm_kernel(const int* __restrict__ indices, const float* __restrict__ vals,
                                   const float* __restrict__ x, float* __restrict__ out,
                                   int nnz, int batch, int size) {
  int n = blockIdx.x;
  if (n >= nnz) return;
  int i = indices[(size_t)n * 2];
  int j = indices[(size_t)n * 2 + 1];
  float v = vals[n];
  for (int b = threadIdx.x; b < batch; b += blockDim.x) {
    atomicAdd(&out[(size_t)b * size + i], v * x[(size_t)b * size + j]);
  }
}

extern "C" void kernel_launch(void* const* d_in, const int* in_sizes, int n_in,
                              void* d_out, int out_size, void* d_ws, size_t ws_size,
                              hipStream_t stream) {
  const float* x       = (const float*)d_in[0];
  const float* values  = (const float*)d_in[1];
  const float* biases  = (const float*)d_in[2];
  const int*   indices = (const int*)d_in[3];
  float* out = (float*)d_out;

  const int size    = in_sizes[2];        // 40000
  const int nnz     = in_sizes[1];        // 5,120,000
  const int batch   = in_sizes[0] / size; // 1024
  const int E       = nnz / 16;           // 320,000
  const int n_nodes = size / 4;           // 10,000
  const int n_vr    = n_nodes * 4;        // virtual rows (row x tile)
  const int ts      = (n_nodes + 3) / 4;  // column tile size in nodes

  // ---- workspace layout ----
  char* ws = (char*)d_ws;
  size_t off = 0;
  int* cnt = (int*)(ws + off);         off += (size_t)n_vr * 4;
  int* cursor = (int*)(ws + off);      off += (size_t)n_vr * 4;
  int* qcnt = (int*)(ws + off);        off += 8 * 4;
  int* row_start4 = (int*)(ws + off);  off += ((size_t)n_vr + 1) * 4;
  off = (off + 255) & ~(size_t)255;
  int* partial = (int*)(ws + off);     off += 256 * 4;
  int* offs = (int*)(ws + off);        off += 256 * 4;
  off = (off + 255) & ~(size_t)255;
  int* col_sorted = (int*)(ws + off);  off += (size_t)E * 4;
  off = (off + 255) & ~(size_t)255;
  int2* rc = (int2*)(ws + off);        off += (size_t)E * 8;
  off = (off + 255) & ~(size_t)255;
  _Float16* vals_h = (_Float16*)(ws + off); off += (size_t)E * 32;
  off = (off + 255) & ~(size_t)255;
  size_t need_csr = off;
  uint2* xh = (uint2*)(ws + off);
  off += (size_t)(size / 4) * batch * 8;
  size_t need_full = off;

  const int n_quads = (n_nodes + 3) / 4;
  const int nb = (n_vr + 255) / 256;
  const int nwin = batch / 64;            // 64-batch windows

  bool queued_ok = (ws_size >= need_full) && (batch % 64 == 0) &&
                   (nwin % 8 == 0) && (nb <= 256);

  if (queued_ok) {
    // zero cnt + cursor + qcnt (contiguous)
    hipMemsetAsync(cnt, 0, ((size_t)2 * n_vr + 8) * 4, stream);

    int npx = (size + 63) / 64;
    int npy = (batch + 63) / 64;
    int npack = npx * npy;
    int nhist = (E + 255) / 256;
    pack_hist_kernel<<<npack + nhist, 256, 0, stream>>>(x, xh, indices, cnt, rc,
                                                        batch, size, E, npx, npack, ts);

    scan_reduce_kernel<<<nb, 256, 0, stream>>>(cnt, partial, n_vr);
    scan_mid_kernel<<<1, 256, 0, stream>>>(partial, offs, nb);
    scan_final_kernel<<<nb, 256, 0, stream>>>(cnt, offs, row_start4, n_vr);

    scatter_vals_kernel<<<(E + 255) / 256, 256, 0, stream>>>(rc, row_start4, cursor,
                                                             values, col_sorted, vals_h, E);

    int nqg = (n_quads + 3) / 4;   // quad-groups (16 rows each)
    int nq = 8;
    int wpq = nwin / nq;
    int total_tasks = nwin * nqg;
    int gridx = total_tasks < 2048 ? total_tasks : 2048;
    spmm_kernel<<<gridx, 256, 0, stream>>>(row_start4, col_sorted, vals_h, xh,
                                           biases, out, n_nodes, batch, size,
                                           qcnt, nq, wpq, nqg);
  } else if (ws_size >= need_csr) {
    hipMemsetAsync(cnt, 0, ((size_t)2 * n_vr + 8) * 4, stream);
    int npx = (size + 63) / 64;
    pack_hist_kernel<<<(E + 255) / 256, 256, 0, stream>>>(x, xh, indices, cnt, rc,
                                                          batch, size, E, npx, 0, ts);
    if (nb <= 256) {
      scan_reduce_kernel<<<nb, 256, 0, stream>>>(cnt, partial, n_vr);
      scan_mid_kernel<<<1, 256, 0, stream>>>(partial, offs, nb);
      scan_final_kernel<<<nb, 256, 0, stream>>>(cnt, offs, row_start4, n_vr);
    } else {
      scan_kernel<<<1, 1024, 0, stream>>>(cnt, row_start4, n_vr);
    }
    scatter_vals_kernel<<<(E + 255) / 256, 256, 0, stream>>>(rc, row_start4, cursor,
                                                             values, col_sorted, vals_h, E);
    dim3 grid(n_quads, (batch + 255) / 256);
    spmm_fb_kernel<<<grid, 256, 0, stream>>>(row_start4, col_sorted, vals_h, x,
                                             biases, out, n_nodes, batch, size);
  } else {
    size_t total = (size_t)batch * size;
    bias_init_kernel<<<(total + 255) / 256, 256, 0, stream>>>(out, biases, batch, size);
    atomic_spmm_kernel<<<nnz, 256, 0, stream>>>(indices, values, x, out, nnz, batch, size);
  }
}

// Round 12
// 310.910 us; speedup vs baseline: 1.8391x; 1.8391x over previous
//
#include <hip/hip_runtime.h>

// y[b, i] = sum v * x[b, j] + biases[i]
// 320k edges, each a dense 4x4 block at (4r, 4c); values row-major per edge.
// Round 12: r10 execution structure (no queues, 4-wave blocks, uint4 2-batch
// pairs/lane, tile-outer column loop over virtual-row CSR, LDS nt epilogue)
// + dispatch-order XCD pinning: w = bx&7 (8 windows of 128 batch), so under
// round-robin block->XCD dispatch each XCD's live xh slice is ~2.56 MB (<L2).

typedef _Float16 h2_t __attribute__((ext_vector_type(2)));
typedef float f4_t __attribute__((ext_vector_type(4)));

__device__ __forceinline__ h2_t as_h2(unsigned u) {
  union { unsigned u; h2_t h; } v; v.u = u; return v.h;
}

__device__ __forceinline__ float fdot2(h2_t a, h2_t b, float c) {
#if __has_builtin(__builtin_amdgcn_fdot2)
  return __builtin_amdgcn_fdot2(a, b, c, false);
#else
  return c + (float)a.x * (float)b.x + (float)a.y * (float)b.y;
#endif
}

// ---- fused pack + hist (virtual rows = row*4 + col-tile) ----
__global__ void pack_hist_kernel(const float* __restrict__ x, uint2* __restrict__ xh,
                                 const int* __restrict__ indices, int* __restrict__ cnt,
                                 int2* __restrict__ rc, int batch, int size, int E,
                                 int npx, int npack, int ts) {
  __shared__ float tile[64][65];
  int bid = blockIdx.x;
  if (bid < npack) {
    int bx = bid % npx, by = bid / npx;
    int c0 = bx * 64;
    int b0 = by * 64;
    int tx = threadIdx.x & 63, ty = threadIdx.x >> 6;
#pragma unroll
    for (int k = 0; k < 64; k += 4) {
      int b = b0 + ty + k, c = c0 + tx;
      if (b < batch && c < size) tile[ty + k][tx] = x[(size_t)b * size + c];
    }
    __syncthreads();
#pragma unroll
    for (int it = 0; it < 4; ++it) {
      int idx = it * 256 + threadIdx.x;
      int cn_local = idx >> 6;
      int bl = idx & 63;
      int c_node = (c0 >> 2) + cn_local;
      int b = b0 + bl;
      if (b < batch && (c_node * 4 + 3) < size) {
        union { _Float16 h[4]; uint2 u; } cv;
        cv.h[0] = (_Float16)tile[bl][cn_local * 4 + 0];
        cv.h[1] = (_Float16)tile[bl][cn_local * 4 + 1];
        cv.h[2] = (_Float16)tile[bl][cn_local * 4 + 2];
        cv.h[3] = (_Float16)tile[bl][cn_local * 4 + 3];
        xh[(size_t)c_node * batch + b] = cv.u;
      }
    }
  } else {
    int e = (bid - npack) * 256 + threadIdx.x;
    if (e < E) {
      int2 ij = *(const int2*)(indices + (size_t)e * 32);
      int r = ij.x >> 2, c = ij.y >> 2;
      int t = (c >= ts) + (c >= 2 * ts) + (c >= 3 * ts);
      int vr = (r << 2) + t;
      rc[e] = make_int2(vr, c);
      atomicAdd(&cnt[vr], 1);
    }
  }
}

// ---- parallel scan over n_vr counts ----
__global__ void scan_reduce_kernel(const int* __restrict__ cnt, int* __restrict__ partial, int n) {
  __shared__ int sh[256];
  int i = blockIdx.x * 256 + threadIdx.x;
  sh[threadIdx.x] = (i < n) ? cnt[i] : 0;
  __syncthreads();
  for (int off = 128; off > 0; off >>= 1) {
    if (threadIdx.x < off) sh[threadIdx.x] += sh[threadIdx.x + off];
    __syncthreads();
  }
  if (threadIdx.x == 0) partial[blockIdx.x] = sh[0];
}

__global__ void scan_mid_kernel(const int* __restrict__ partial, int* __restrict__ offs, int nb) {
  __shared__ int sh[256];
  int t = threadIdx.x;
  sh[t] = (t < nb) ? partial[t] : 0;
  __syncthreads();
  for (int off = 1; off < 256; off <<= 1) {
    int add = (t >= off) ? sh[t - off] : 0;
    __syncthreads();
    sh[t] += add;
    __syncthreads();
  }
  if (t < nb) offs[t] = sh[t];  // inclusive
}

__global__ void scan_final_kernel(const int* __restrict__ cnt, const int* __restrict__ offs,
                                  int* __restrict__ row_start, int n) {
  __shared__ int sh[256];
  int blk = blockIdx.x;
  int i = blk * 256 + threadIdx.x;
  int v = (i < n) ? cnt[i] : 0;
  sh[threadIdx.x] = v;
  __syncthreads();
  for (int off = 1; off < 256; off <<= 1) {
    int add = (threadIdx.x >= off) ? sh[threadIdx.x - off] : 0;
    __syncthreads();
    sh[threadIdx.x] += add;
    __syncthreads();
  }
  int base = (blk == 0) ? 0 : offs[blk - 1];
  if (i < n) row_start[i + 1] = sh[threadIdx.x] + base;
  if (blk == 0 && threadIdx.x == 0) row_start[0] = 0;
}

__global__ void scan_kernel(const int* __restrict__ cnt, int* __restrict__ row_start, int n) {
  __shared__ int buf[1024];
  __shared__ int carry_s;
  int t = threadIdx.x;
  if (t == 0) { carry_s = 0; row_start[0] = 0; }
  __syncthreads();
  for (int base = 0; base < n; base += 1024) {
    int v = (base + t < n) ? cnt[base + t] : 0;
    buf[t] = v;
    __syncthreads();
    for (int off = 1; off < 1024; off <<= 1) {
      int add = (t >= off) ? buf[t - off] : 0;
      __syncthreads();
      buf[t] += add;
      __syncthreads();
    }
    if (base + t < n) row_start[base + t + 1] = buf[t] + carry_s;
    __syncthreads();
    if (t == 0) carry_s += buf[1023];
    __syncthreads();
  }
}

// ---- fused scatter + vals fp16 conversion (virtual-row CSR order) ----
__global__ void scatter_vals_kernel(const int2* __restrict__ rc, const int* __restrict__ row_start,
                                    int* __restrict__ cursor, const float* __restrict__ vals,
                                    int* __restrict__ col_sorted, _Float16* __restrict__ vals_h,
                                    int E) {
  int e = blockIdx.x * blockDim.x + threadIdx.x;
  if (e >= E) return;
  int2 v = rc[e];
  int pos = row_start[v.x] + atomicAdd(&cursor[v.x], 1);
  col_sorted[pos] = v.y;
  const float* src = vals + (size_t)e * 16;
  union { _Float16 h[8]; uint4 u; } w0, w1;
#pragma unroll
  for (int i = 0; i < 8; ++i) w0.h[i] = (_Float16)src[i];
#pragma unroll
  for (int i = 0; i < 8; ++i) w1.h[i] = (_Float16)src[8 + i];
  *(uint4*)(vals_h + (size_t)pos * 16) = w0.u;
  *(uint4*)(vals_h + (size_t)pos * 16 + 8) = w1.u;
}

// One edge, two batch elements (X = 4 fp16 of b0, then 4 fp16 of b1).
__device__ __forceinline__ void edge_acc2(const _Float16* __restrict__ vh, size_t p,
                                          uint4 X, float* __restrict__ a0,
                                          float* __restrict__ a1) {
  uint4 A = *(const uint4*)(vh + p * 16);
  uint4 C = *(const uint4*)(vh + p * 16 + 8);
  h2_t x01a = as_h2(X.x), x23a = as_h2(X.y);
  h2_t x01b = as_h2(X.z), x23b = as_h2(X.w);
  a0[0] = fdot2(as_h2(A.x), x01a, a0[0]); a0[0] = fdot2(as_h2(A.y), x23a, a0[0]);
  a0[1] = fdot2(as_h2(A.z), x01a, a0[1]); a0[1] = fdot2(as_h2(A.w), x23a, a0[1]);
  a0[2] = fdot2(as_h2(C.x), x01a, a0[2]); a0[2] = fdot2(as_h2(C.y), x23a, a0[2]);
  a0[3] = fdot2(as_h2(C.z), x01a, a0[3]); a0[3] = fdot2(as_h2(C.w), x23a, a0[3]);
  a1[0] = fdot2(as_h2(A.x), x01b, a1[0]); a1[0] = fdot2(as_h2(A.y), x23b, a1[0]);
  a1[1] = fdot2(as_h2(A.z), x01b, a1[1]); a1[1] = fdot2(as_h2(A.w), x23b, a1[1]);
  a1[2] = fdot2(as_h2(C.x), x01b, a1[2]); a1[2] = fdot2(as_h2(C.y), x23b, a1[2]);
  a1[3] = fdot2(as_h2(C.z), x01b, a1[3]); a1[3] = fdot2(as_h2(C.w), x23b, a1[3]);
}

// spmm: block = 4 waves x one quad each; one 128-batch window per block.
// slot8: w = bx&7 -> under round-robin dispatch, XCD k runs only window k.
// Tile-outer column loop (virtual CSR) keeps the live slice ~2.56 MB.
__global__ __launch_bounds__(256) void spmm_kernel(
    const int* __restrict__ row_start4, const int* __restrict__ col_sorted,
    const _Float16* __restrict__ vals_h, const uint4* __restrict__ xh4,
    const float* __restrict__ biases, float* __restrict__ out,
    int n_nodes, int batch, int size, int nqg, int slot8) {
  __shared__ float tile[64][68];
  int bx = blockIdx.x;
  int w, qg;
  if (slot8) { w = bx & 7; qg = bx >> 3; }
  else       { w = bx / nqg; qg = bx - w * nqg; }
  int wave = threadIdx.x >> 6;
  int lane = threadIdx.x & 63;
  int quad = qg * 4 + wave;
  bool qvalid = (quad * 4 < n_nodes);
  int bhalf = batch >> 1;
  int bh = w * 64 + lane;
  bool bvalid = (bh < bhalf);
  int bhc = bvalid ? bh : bhalf - 1;
  const uint4* __restrict__ xb = xh4 + bhc;

  float acc[4][2][4];
#pragma unroll
  for (int i = 0; i < 32; ++i) ((float*)acc)[i] = 0.f;

  if (qvalid) {
#pragma unroll
    for (int t = 0; t < 4; ++t) {       // column tile: OUTER (phase-aligned)
#pragma unroll
      for (int rr = 0; rr < 4; ++rr) {
        int r = quad * 4 + rr;
        if (r >= n_nodes) continue;
        int vr = (r << 2) + t;
        int s = __builtin_amdgcn_readfirstlane(row_start4[vr]);
        int e = __builtin_amdgcn_readfirstlane(row_start4[vr + 1]);
        float* a0 = acc[rr][0];
        float* a1 = acc[rr][1];
        int p = s;
        for (; p + 3 < e; p += 4) {
          int c0 = col_sorted[p];
          int c1 = col_sorted[p + 1];
          int c2 = col_sorted[p + 2];
          int c3 = col_sorted[p + 3];
          uint4 X0 = xb[(size_t)c0 * bhalf];
          uint4 X1 = xb[(size_t)c1 * bhalf];
          uint4 X2 = xb[(size_t)c2 * bhalf];
          uint4 X3 = xb[(size_t)c3 * bhalf];
          edge_acc2(vals_h, (size_t)p,     X0, a0, a1);
          edge_acc2(vals_h, (size_t)p + 1, X1, a0, a1);
          edge_acc2(vals_h, (size_t)p + 2, X2, a0, a1);
          edge_acc2(vals_h, (size_t)p + 3, X3, a0, a1);
        }
        for (; p < e; ++p) {
          uint4 X = xb[(size_t)col_sorted[p] * bhalf];
          edge_acc2(vals_h, (size_t)p, X, a0, a1);
        }
      }
    }
  }

  // ---- epilogue: LDS transpose -> full-line nontemporal stores ----
#pragma unroll
  for (int ph = 0; ph < 2; ++ph) {
    __syncthreads();
    if (qvalid && bvalid && (lane >> 5) == ph) {
      int lb = lane & 31;
#pragma unroll
      for (int rr = 0; rr < 4; ++rr) {
        int r = quad * 4 + rr;
        if (r < n_nodes) {
          float4 bias = *(const float4*)&biases[r << 2];
#pragma unroll
          for (int j = 0; j < 2; ++j) {
            float4 o = make_float4(acc[rr][j][0] + bias.x, acc[rr][j][1] + bias.y,
                                   acc[rr][j][2] + bias.z, acc[rr][j][3] + bias.w);
            *(float4*)&tile[lb * 2 + j][wave * 16 + rr * 4] = o;
          }
        }
      }
    }
    __syncthreads();
#pragma unroll
    for (int it = 0; it < 4; ++it) {
      int idx = it * 256 + threadIdx.x;
      int bl = idx >> 4;
      int f4 = idx & 15;
      int r = qg * 16 + f4;
      int b = w * 128 + ph * 64 + bl;
      if (r < n_nodes && b < batch) {
        f4_t v = *(f4_t*)&tile[bl][f4 * 4];
        __builtin_nontemporal_store(v, (f4_t*)&out[(size_t)b * size + (size_t)r * 4]);
      }
    }
  }
}

// Fallback when ws can't hold xh: gather fp32 x directly, fp16 V (virtual-row CSR).
__global__ __launch_bounds__(256) void spmm_fb_kernel(
    const int* __restrict__ row_start4, const int* __restrict__ col_sorted,
    const _Float16* __restrict__ vals_h, const float* __restrict__ x,
    const float* __restrict__ biases, float* __restrict__ out,
    int n_nodes, int batch, int size) {
  int quad = blockIdx.x;
  int b = blockIdx.y * blockDim.x + threadIdx.x;
  if (b >= batch || quad * 4 >= n_nodes) return;
  float acc[4][4];
#pragma unroll
  for (int i = 0; i < 16; ++i) ((float*)acc)[i] = 0.f;
#pragma unroll
  for (int rr = 0; rr < 4; ++rr) {
    int r = quad * 4 + rr;
    if (r >= n_nodes) break;
    int s = row_start4[r << 2], e = row_start4[(r << 2) + 4];  // all 4 tiles
    for (int p = s; p < e; ++p) {
      int c = col_sorted[p];
      float4 xv = *(const float4*)&x[(size_t)b * size + (c << 2)];
      const _Float16* V = vals_h + (size_t)p * 16;
#pragma unroll
      for (int i = 0; i < 4; ++i) {
        acc[rr][i] += (float)V[i * 4 + 0] * xv.x + (float)V[i * 4 + 1] * xv.y +
                      (float)V[i * 4 + 2] * xv.z + (float)V[i * 4 + 3] * xv.w;
      }
    }
  }
#pragma unroll
  for (int rr = 0; rr < 4; ++rr) {
    int r = quad * 4 + rr;
    if (r >= n_nodes) break;
    float4 bias = *(const float4*)&biases[r << 2];
    float4 o = make_float4(acc[rr][0] + bias.x, acc[rr][1] + bias.y,
                           acc[rr][2] + bias.z, acc[rr][3] + bias.w);
    *(float4*)&out[(size_t)b * size + (r << 2)] = o;
  }
}

// Last-resort fallback (tiny ws)
__global__ void bias_init_kernel(float* __restrict__ out, const float* __restrict__ biases,
                                 int batch, int size) {
  size_t t = (size_t)blockIdx.x * blockDim.x + threadIdx.x;
  size_t total = (size_t)batch * size;
  if (t >= total) return;
  out[t] = biases[t % size];
}

__global__ void atomic_spmm_kernel(const int* __restrict__ indices, const float* __restrict__ vals,
                                   const float* __restrict__ x, float* __restrict__ out,
                                   int nnz, int batch, int size) {
  int n = blockIdx.x;
  if (n >= nnz) return;
  int i = indices[(size_t)n * 2];
  int j = indices[(size_t)n * 2 + 1];
  float v = vals[n];
  for (int b = threadIdx.x; b < batch; b += blockDim.x) {
    atomicAdd(&out[(size_t)b * size + i], v * x[(size_t)b * size + j]);
  }
}

extern "C" void kernel_launch(void* const* d_in, const int* in_sizes, int n_in,
                              void* d_out, int out_size, void* d_ws, size_t ws_size,
                              hipStream_t stream) {
  const float* x       = (const float*)d_in[0];
  const float* values  = (const float*)d_in[1];
  const float* biases  = (const float*)d_in[2];
  const int*   indices = (const int*)d_in[3];
  float* out = (float*)d_out;

  const int size    = in_sizes[2];        // 40000
  const int nnz     = in_sizes[1];        // 5,120,000
  const int batch   = in_sizes[0] / size; // 1024
  const int E       = nnz / 16;           // 320,000
  const int n_nodes = size / 4;           // 10,000
  const int n_vr    = n_nodes * 4;        // virtual rows (row x tile)
  const int ts      = (n_nodes + 3) / 4;  // column tile size in nodes

  // ---- workspace layout ----
  char* ws = (char*)d_ws;
  size_t off = 0;
  int* cnt = (int*)(ws + off);         off += (size_t)n_vr * 4;
  int* cursor = (int*)(ws + off);      off += (size_t)n_vr * 4;
  int* row_start4 = (int*)(ws + off);  off += ((size_t)n_vr + 1) * 4;
  off = (off + 255) & ~(size_t)255;
  int* partial = (int*)(ws + off);     off += 256 * 4;
  int* offs = (int*)(ws + off);        off += 256 * 4;
  off = (off + 255) & ~(size_t)255;
  int* col_sorted = (int*)(ws + off);  off += (size_t)E * 4;
  off = (off + 255) & ~(size_t)255;
  int2* rc = (int2*)(ws + off);        off += (size_t)E * 8;
  off = (off + 255) & ~(size_t)255;
  _Float16* vals_h = (_Float16*)(ws + off); off += (size_t)E * 32;
  off = (off + 255) & ~(size_t)255;
  size_t need_csr = off;
  uint2* xh = (uint2*)(ws + off);
  off += (size_t)(size / 4) * batch * 8;
  size_t need_full = off;

  const int n_quads = (n_nodes + 3) / 4;
  const int nb = (n_vr + 255) / 256;

  if (ws_size >= need_full && (batch & 1) == 0 && nb <= 256) {
    hipMemsetAsync(cnt, 0, (size_t)2 * n_vr * 4, stream);  // cnt + cursor

    int npx = (size + 63) / 64;
    int npy = (batch + 63) / 64;
    int npack = npx * npy;
    int nhist = (E + 255) / 256;
    pack_hist_kernel<<<npack + nhist, 256, 0, stream>>>(x, xh, indices, cnt, rc,
                                                        batch, size, E, npx, npack, ts);

    scan_reduce_kernel<<<nb, 256, 0, stream>>>(cnt, partial, n_vr);
    scan_mid_kernel<<<1, 256, 0, stream>>>(partial, offs, nb);
    scan_final_kernel<<<nb, 256, 0, stream>>>(cnt, offs, row_start4, n_vr);

    scatter_vals_kernel<<<(E + 255) / 256, 256, 0, stream>>>(rc, row_start4, cursor,
                                                             values, col_sorted, vals_h, E);

    int nqg = (n_quads + 3) / 4;          // quad-groups of 4 (1 per wave)
    int nwin = (batch / 2 + 63) / 64;     // 128-batch windows (64 pairs)
    int slot8 = (nwin == 8) ? 1 : 0;      // dispatch-order XCD pinning
    spmm_kernel<<<nwin * nqg, 256, 0, stream>>>(row_start4, col_sorted, vals_h,
                                                (const uint4*)xh, biases, out,
                                                n_nodes, batch, size, nqg, slot8);
  } else if (ws_size >= need_csr) {
    hipMemsetAsync(cnt, 0, (size_t)2 * n_vr * 4, stream);
    int npx = (size + 63) / 64;
    pack_hist_kernel<<<(E + 255) / 256, 256, 0, stream>>>(x, xh, indices, cnt, rc,
                                                          batch, size, E, npx, 0, ts);
    if (nb <= 256) {
      scan_reduce_kernel<<<nb, 256, 0, stream>>>(cnt, partial, n_vr);
      scan_mid_kernel<<<1, 256, 0, stream>>>(partial, offs, nb);
      scan_final_kernel<<<nb, 256, 0, stream>>>(cnt, offs, row_start4, n_vr);
    } else {
      scan_kernel<<<1, 1024, 0, stream>>>(cnt, row_start4, n_vr);
    }
    scatter_vals_kernel<<<(E + 255) / 256, 256, 0, stream>>>(rc, row_start4, cursor,
                                                             values, col_sorted, vals_h, E);
    dim3 grid(n_quads, (batch + 255) / 256);
    spmm_fb_kernel<<<grid, 256, 0, stream>>>(row_start4, col_sorted, vals_h, x,
                                             biases, out, n_nodes, batch, size);
  } else {
    size_t total = (size_t)batch * size;
    bias_init_kernel<<<(total + 255) / 256, 256, 0, stream>>>(out, biases, batch, size);
    atomic_spmm_kernel<<<nnz, 256, 0, stream>>>(indices, values, x, out, nnz, batch, size);
  }
}

// Round 14
// 301.535 us; speedup vs baseline: 1.8963x; 1.0311x over previous
//
#include <hip/hip_runtime.h>

// y[b, i] = sum v * x[b, j] + biases[i]
// 320k edges, each a dense 4x4 block at (4r, 4c); values row-major per edge.
// Round 14 (= r13 with compile fix): r12 verbatim + nontemporal loads for
// vals_h via ext_vector_type (V stream has zero per-XCD reuse; nt ->
// evict-first in L2, protects the pinned xh slice).

typedef _Float16 h2_t __attribute__((ext_vector_type(2)));
typedef float f4_t __attribute__((ext_vector_type(4)));
typedef unsigned u4_t __attribute__((ext_vector_type(4)));

__device__ __forceinline__ h2_t as_h2(unsigned u) {
  union { unsigned u; h2_t h; } v; v.u = u; return v.h;
}

__device__ __forceinline__ float fdot2(h2_t a, h2_t b, float c) {
#if __has_builtin(__builtin_amdgcn_fdot2)
  return __builtin_amdgcn_fdot2(a, b, c, false);
#else
  return c + (float)a.x * (float)b.x + (float)a.y * (float)b.y;
#endif
}

__device__ __forceinline__ u4_t ntload4(const u4_t* p) {
#if __has_builtin(__builtin_nontemporal_load)
  return __builtin_nontemporal_load(p);
#else
  return *p;
#endif
}

// ---- fused pack + hist (virtual rows = row*4 + col-tile) ----
__global__ void pack_hist_kernel(const float* __restrict__ x, uint2* __restrict__ xh,
                                 const int* __restrict__ indices, int* __restrict__ cnt,
                                 int2* __restrict__ rc, int batch, int size, int E,
                                 int npx, int npack, int ts) {
  __shared__ float tile[64][65];
  int bid = blockIdx.x;
  if (bid < npack) {
    int bx = bid % npx, by = bid / npx;
    int c0 = bx * 64;
    int b0 = by * 64;
    int tx = threadIdx.x & 63, ty = threadIdx.x >> 6;
#pragma unroll
    for (int k = 0; k < 64; k += 4) {
      int b = b0 + ty + k, c = c0 + tx;
      if (b < batch && c < size) tile[ty + k][tx] = x[(size_t)b * size + c];
    }
    __syncthreads();
#pragma unroll
    for (int it = 0; it < 4; ++it) {
      int idx = it * 256 + threadIdx.x;
      int cn_local = idx >> 6;
      int bl = idx & 63;
      int c_node = (c0 >> 2) + cn_local;
      int b = b0 + bl;
      if (b < batch && (c_node * 4 + 3) < size) {
        union { _Float16 h[4]; uint2 u; } cv;
        cv.h[0] = (_Float16)tile[bl][cn_local * 4 + 0];
        cv.h[1] = (_Float16)tile[bl][cn_local * 4 + 1];
        cv.h[2] = (_Float16)tile[bl][cn_local * 4 + 2];
        cv.h[3] = (_Float16)tile[bl][cn_local * 4 + 3];
        xh[(size_t)c_node * batch + b] = cv.u;
      }
    }
  } else {
    int e = (bid - npack) * 256 + threadIdx.x;
    if (e < E) {
      int2 ij = *(const int2*)(indices + (size_t)e * 32);
      int r = ij.x >> 2, c = ij.y >> 2;
      int t = (c >= ts) + (c >= 2 * ts) + (c >= 3 * ts);
      int vr = (r << 2) + t;
      rc[e] = make_int2(vr, c);
      atomicAdd(&cnt[vr], 1);
    }
  }
}

// ---- parallel scan over n_vr counts ----
__global__ void scan_reduce_kernel(const int* __restrict__ cnt, int* __restrict__ partial, int n) {
  __shared__ int sh[256];
  int i = blockIdx.x * 256 + threadIdx.x;
  sh[threadIdx.x] = (i < n) ? cnt[i] : 0;
  __syncthreads();
  for (int off = 128; off > 0; off >>= 1) {
    if (threadIdx.x < off) sh[threadIdx.x] += sh[threadIdx.x + off];
    __syncthreads();
  }
  if (threadIdx.x == 0) partial[blockIdx.x] = sh[0];
}

__global__ void scan_mid_kernel(const int* __restrict__ partial, int* __restrict__ offs, int nb) {
  __shared__ int sh[256];
  int t = threadIdx.x;
  sh[t] = (t < nb) ? partial[t] : 0;
  __syncthreads();
  for (int off = 1; off < 256; off <<= 1) {
    int add = (t >= off) ? sh[t - off] : 0;
    __syncthreads();
    sh[t] += add;
    __syncthreads();
  }
  if (t < nb) offs[t] = sh[t];  // inclusive
}

__global__ void scan_final_kernel(const int* __restrict__ cnt, const int* __restrict__ offs,
                                  int* __restrict__ row_start, int n) {
  __shared__ int sh[256];
  int blk = blockIdx.x;
  int i = blk * 256 + threadIdx.x;
  int v = (i < n) ? cnt[i] : 0;
  sh[threadIdx.x] = v;
  __syncthreads();
  for (int off = 1; off < 256; off <<= 1) {
    int add = (threadIdx.x >= off) ? sh[threadIdx.x - off] : 0;
    __syncthreads();
    sh[threadIdx.x] += add;
    __syncthreads();
  }
  int base = (blk == 0) ? 0 : offs[blk - 1];
  if (i < n) row_start[i + 1] = sh[threadIdx.x] + base;
  if (blk == 0 && threadIdx.x == 0) row_start[0] = 0;
}

__global__ void scan_kernel(const int* __restrict__ cnt, int* __restrict__ row_start, int n) {
  __shared__ int buf[1024];
  __shared__ int carry_s;
  int t = threadIdx.x;
  if (t == 0) { carry_s = 0; row_start[0] = 0; }
  __syncthreads();
  for (int base = 0; base < n; base += 1024) {
    int v = (base + t < n) ? cnt[base + t] : 0;
    buf[t] = v;
    __syncthreads();
    for (int off = 1; off < 1024; off <<= 1) {
      int add = (t >= off) ? buf[t - off] : 0;
      __syncthreads();
      buf[t] += add;
      __syncthreads();
    }
    if (base + t < n) row_start[base + t + 1] = buf[t] + carry_s;
    __syncthreads();
    if (t == 0) carry_s += buf[1023];
    __syncthreads();
  }
}

// ---- fused scatter + vals fp16 conversion (virtual-row CSR order) ----
__global__ void scatter_vals_kernel(const int2* __restrict__ rc, const int* __restrict__ row_start,
                                    int* __restrict__ cursor, const float* __restrict__ vals,
                                    int* __restrict__ col_sorted, _Float16* __restrict__ vals_h,
                                    int E) {
  int e = blockIdx.x * blockDim.x + threadIdx.x;
  if (e >= E) return;
  int2 v = rc[e];
  int pos = row_start[v.x] + atomicAdd(&cursor[v.x], 1);
  col_sorted[pos] = v.y;
  const float* src = vals + (size_t)e * 16;
  union { _Float16 h[8]; uint4 u; } w0, w1;
#pragma unroll
  for (int i = 0; i < 8; ++i) w0.h[i] = (_Float16)src[i];
#pragma unroll
  for (int i = 0; i < 8; ++i) w1.h[i] = (_Float16)src[8 + i];
  *(uint4*)(vals_h + (size_t)pos * 16) = w0.u;
  *(uint4*)(vals_h + (size_t)pos * 16 + 8) = w1.u;
}

// One edge, two batch elements (X = 4 fp16 of b0, then 4 fp16 of b1).
// V loads are nontemporal: zero per-XCD reuse, keep them out of L2 residency.
__device__ __forceinline__ void edge_acc2(const _Float16* __restrict__ vh, size_t p,
                                          uint4 X, float* __restrict__ a0,
                                          float* __restrict__ a1) {
  u4_t A = ntload4((const u4_t*)(vh + p * 16));
  u4_t C = ntload4((const u4_t*)(vh + p * 16 + 8));
  h2_t x01a = as_h2(X.x), x23a = as_h2(X.y);
  h2_t x01b = as_h2(X.z), x23b = as_h2(X.w);
  a0[0] = fdot2(as_h2(A[0]), x01a, a0[0]); a0[0] = fdot2(as_h2(A[1]), x23a, a0[0]);
  a0[1] = fdot2(as_h2(A[2]), x01a, a0[1]); a0[1] = fdot2(as_h2(A[3]), x23a, a0[1]);
  a0[2] = fdot2(as_h2(C[0]), x01a, a0[2]); a0[2] = fdot2(as_h2(C[1]), x23a, a0[2]);
  a0[3] = fdot2(as_h2(C[2]), x01a, a0[3]); a0[3] = fdot2(as_h2(C[3]), x23a, a0[3]);
  a1[0] = fdot2(as_h2(A[0]), x01b, a1[0]); a1[0] = fdot2(as_h2(A[1]), x23b, a1[0]);
  a1[1] = fdot2(as_h2(A[2]), x01b, a1[1]); a1[1] = fdot2(as_h2(A[3]), x23b, a1[1]);
  a1[2] = fdot2(as_h2(C[0]), x01b, a1[2]); a1[2] = fdot2(as_h2(C[1]), x23b, a1[2]);
  a1[3] = fdot2(as_h2(C[2]), x01b, a1[3]); a1[3] = fdot2(as_h2(C[3]), x23b, a1[3]);
}

// spmm: block = 4 waves x one quad each; one 128-batch window per block.
// slot8: w = bx&7 -> under round-robin dispatch, XCD k runs only window k.
// Tile-outer column loop (virtual CSR) keeps the live slice ~2.56 MB.
__global__ __launch_bounds__(256) void spmm_kernel(
    const int* __restrict__ row_start4, const int* __restrict__ col_sorted,
    const _Float16* __restrict__ vals_h, const uint4* __restrict__ xh4,
    const float* __restrict__ biases, float* __restrict__ out,
    int n_nodes, int batch, int size, int nqg, int slot8) {
  __shared__ float tile[64][68];
  int bx = blockIdx.x;
  int w, qg;
  if (slot8) { w = bx & 7; qg = bx >> 3; }
  else       { w = bx / nqg; qg = bx - w * nqg; }
  int wave = threadIdx.x >> 6;
  int lane = threadIdx.x & 63;
  int quad = qg * 4 + wave;
  bool qvalid = (quad * 4 < n_nodes);
  int bhalf = batch >> 1;
  int bh = w * 64 + lane;
  bool bvalid = (bh < bhalf);
  int bhc = bvalid ? bh : bhalf - 1;
  const uint4* __restrict__ xb = xh4 + bhc;

  float acc[4][2][4];
#pragma unroll
  for (int i = 0; i < 32; ++i) ((float*)acc)[i] = 0.f;

  if (qvalid) {
#pragma unroll
    for (int t = 0; t < 4; ++t) {       // column tile: OUTER (phase-aligned)
#pragma unroll
      for (int rr = 0; rr < 4; ++rr) {
        int r = quad * 4 + rr;
        if (r >= n_nodes) continue;
        int vr = (r << 2) + t;
        int s = __builtin_amdgcn_readfirstlane(row_start4[vr]);
        int e = __builtin_amdgcn_readfirstlane(row_start4[vr + 1]);
        float* a0 = acc[rr][0];
        float* a1 = acc[rr][1];
        int p = s;
        for (; p + 3 < e; p += 4) {
          int c0 = col_sorted[p];
          int c1 = col_sorted[p + 1];
          int c2 = col_sorted[p + 2];
          int c3 = col_sorted[p + 3];
          uint4 X0 = xb[(size_t)c0 * bhalf];
          uint4 X1 = xb[(size_t)c1 * bhalf];
          uint4 X2 = xb[(size_t)c2 * bhalf];
          uint4 X3 = xb[(size_t)c3 * bhalf];
          edge_acc2(vals_h, (size_t)p,     X0, a0, a1);
          edge_acc2(vals_h, (size_t)p + 1, X1, a0, a1);
          edge_acc2(vals_h, (size_t)p + 2, X2, a0, a1);
          edge_acc2(vals_h, (size_t)p + 3, X3, a0, a1);
        }
        for (; p < e; ++p) {
          uint4 X = xb[(size_t)col_sorted[p] * bhalf];
          edge_acc2(vals_h, (size_t)p, X, a0, a1);
        }
      }
    }
  }

  // ---- epilogue: LDS transpose -> full-line nontemporal stores ----
#pragma unroll
  for (int ph = 0; ph < 2; ++ph) {
    __syncthreads();
    if (qvalid && bvalid && (lane >> 5) == ph) {
      int lb = lane & 31;
#pragma unroll
      for (int rr = 0; rr < 4; ++rr) {
        int r = quad * 4 + rr;
        if (r < n_nodes) {
          float4 bias = *(const float4*)&biases[r << 2];
#pragma unroll
          for (int j = 0; j < 2; ++j) {
            float4 o = make_float4(acc[rr][j][0] + bias.x, acc[rr][j][1] + bias.y,
                                   acc[rr][j][2] + bias.z, acc[rr][j][3] + bias.w);
            *(float4*)&tile[lb * 2 + j][wave * 16 + rr * 4] = o;
          }
        }
      }
    }
    __syncthreads();
#pragma unroll
    for (int it = 0; it < 4; ++it) {
      int idx = it * 256 + threadIdx.x;
      int bl = idx >> 4;
      int f4 = idx & 15;
      int r = qg * 16 + f4;
      int b = w * 128 + ph * 64 + bl;
      if (r < n_nodes && b < batch) {
        f4_t v = *(f4_t*)&tile[bl][f4 * 4];
        __builtin_nontemporal_store(v, (f4_t*)&out[(size_t)b * size + (size_t)r * 4]);
      }
    }
  }
}

// Fallback when ws can't hold xh: gather fp32 x directly, fp16 V (virtual-row CSR).
__global__ __launch_bounds__(256) void spmm_fb_kernel(
    const int* __restrict__ row_start4, const int* __restrict__ col_sorted,
    const _Float16* __restrict__ vals_h, const float* __restrict__ x,
    const float* __restrict__ biases, float* __restrict__ out,
    int n_nodes, int batch, int size) {
  int quad = blockIdx.x;
  int b = blockIdx.y * blockDim.x + threadIdx.x;
  if (b >= batch || quad * 4 >= n_nodes) return;
  float acc[4][4];
#pragma unroll
  for (int i = 0; i < 16; ++i) ((float*)acc)[i] = 0.f;
#pragma unroll
  for (int rr = 0; rr < 4; ++rr) {
    int r = quad * 4 + rr;
    if (r >= n_nodes) break;
    int s = row_start4[r << 2], e = row_start4[(r << 2) + 4];  // all 4 tiles
    for (int p = s; p < e; ++p) {
      int c = col_sorted[p];
      float4 xv = *(const float4*)&x[(size_t)b * size + (c << 2)];
      const _Float16* V = vals_h + (size_t)p * 16;
#pragma unroll
      for (int i = 0; i < 4; ++i) {
        acc[rr][i] += (float)V[i * 4 + 0] * xv.x + (float)V[i * 4 + 1] * xv.y +
                      (float)V[i * 4 + 2] * xv.z + (float)V[i * 4 + 3] * xv.w;
      }
    }
  }
#pragma unroll
  for (int rr = 0; rr < 4; ++rr) {
    int r = quad * 4 + rr;
    if (r >= n_nodes) break;
    float4 bias = *(const float4*)&biases[r << 2];
    float4 o = make_float4(acc[rr][0] + bias.x, acc[rr][1] + bias.y,
                           acc[rr][2] + bias.z, acc[rr][3] + bias.w);
    *(float4*)&out[(size_t)b * size + (r << 2)] = o;
  }
}

// Last-resort fallback (tiny ws)
__global__ void bias_init_kernel(float* __restrict__ out, const float* __restrict__ biases,
                                 int batch, int size) {
  size_t t = (size_t)blockIdx.x * blockDim.x + threadIdx.x;
  size_t total = (size_t)batch * size;
  if (t >= total) return;
  out[t] = biases[t % size];
}

__global__ void atomic_spmm_kernel(const int* __restrict__ indices, const float* __restrict__ vals,
                                   const float* __restrict__ x, float* __restrict__ out,
                                   int nnz, int batch, int size) {
  int n = blockIdx.x;
  if (n >= nnz) return;
  int i = indices[(size_t)n * 2];
  int j = indices[(size_t)n * 2 + 1];
  float v = vals[n];
  for (int b = threadIdx.x; b < batch; b += blockDim.x) {
    atomicAdd(&out[(size_t)b * size + i], v * x[(size_t)b * size + j]);
  }
}

extern "C" void kernel_launch(void* const* d_in, const int* in_sizes, int n_in,
                              void* d_out, int out_size, void* d_ws, size_t ws_size,
                              hipStream_t stream) {
  const float* x       = (const float*)d_in[0];
  const float* values  = (const float*)d_in[1];
  const float* biases  = (const float*)d_in[2];
  const int*   indices = (const int*)d_in[3];
  float* out = (float*)d_out;

  const int size    = in_sizes[2];        // 40000
  const int nnz     = in_sizes[1];        // 5,120,000
  const int batch   = in_sizes[0] / size; // 1024
  const int E       = nnz / 16;           // 320,000
  const int n_nodes = size / 4;           // 10,000
  const int n_vr    = n_nodes * 4;        // virtual rows (row x tile)
  const int ts      = (n_nodes + 3) / 4;  // column tile size in nodes

  // ---- workspace layout ----
  char* ws = (char*)d_ws;
  size_t off = 0;
  int* cnt = (int*)(ws + off);         off += (size_t)n_vr * 4;
  int* cursor = (int*)(ws + off);      off += (size_t)n_vr * 4;
  int* row_start4 = (int*)(ws + off);  off += ((size_t)n_vr + 1) * 4;
  off = (off + 255) & ~(size_t)255;
  int* partial = (int*)(ws + off);     off += 256 * 4;
  int* offs = (int*)(ws + off);        off += 256 * 4;
  off = (off + 255) & ~(size_t)255;
  int* col_sorted = (int*)(ws + off);  off += (size_t)E * 4;
  off = (off + 255) & ~(size_t)255;
  int2* rc = (int2*)(ws + off);        off += (size_t)E * 8;
  off = (off + 255) & ~(size_t)255;
  _Float16* vals_h = (_Float16*)(ws + off); off += (size_t)E * 32;
  off = (off + 255) & ~(size_t)255;
  size_t need_csr = off;
  uint2* xh = (uint2*)(ws + off);
  off += (size_t)(size / 4) * batch * 8;
  size_t need_full = off;

  const int n_quads = (n_nodes + 3) / 4;
  const int nb = (n_vr + 255) / 256;

  if (ws_size >= need_full && (batch & 1) == 0 && nb <= 256) {
    hipMemsetAsync(cnt, 0, (size_t)2 * n_vr * 4, stream);  // cnt + cursor

    int npx = (size + 63) / 64;
    int npy = (batch + 63) / 64;
    int npack = npx * npy;
    int nhist = (E + 255) / 256;
    pack_hist_kernel<<<npack + nhist, 256, 0, stream>>>(x, xh, indices, cnt, rc,
                                                        batch, size, E, npx, npack, ts);

    scan_reduce_kernel<<<nb, 256, 0, stream>>>(cnt, partial, n_vr);
    scan_mid_kernel<<<1, 256, 0, stream>>>(partial, offs, nb);
    scan_final_kernel<<<nb, 256, 0, stream>>>(cnt, offs, row_start4, n_vr);

    scatter_vals_kernel<<<(E + 255) / 256, 256, 0, stream>>>(rc, row_start4, cursor,
                                                             values, col_sorted, vals_h, E);

    int nqg = (n_quads + 3) / 4;          // quad-groups of 4 (1 per wave)
    int nwin = (batch / 2 + 63) / 64;     // 128-batch windows (64 pairs)
    int slot8 = (nwin == 8) ? 1 : 0;      // dispatch-order XCD pinning
    spmm_kernel<<<nwin * nqg, 256, 0, stream>>>(row_start4, col_sorted, vals_h,
                                                (const uint4*)xh, biases, out,
                                                n_nodes, batch, size, nqg, slot8);
  } else if (ws_size >= need_csr) {
    hipMemsetAsync(cnt, 0, (size_t)2 * n_vr * 4, stream);
    int npx = (size + 63) / 64;
    pack_hist_kernel<<<(E + 255) / 256, 256, 0, stream>>>(x, xh, indices, cnt, rc,
                                                          batch, size, E, npx, 0, ts);
    if (nb <= 256) {
      scan_reduce_kernel<<<nb, 256, 0, stream>>>(cnt, partial, n_vr);
      scan_mid_kernel<<<1, 256, 0, stream>>>(partial, offs, nb);
      scan_final_kernel<<<nb, 256, 0, stream>>>(cnt, offs, row_start4, n_vr);
    } else {
      scan_kernel<<<1, 1024, 0, stream>>>(cnt, row_start4, n_vr);
    }
    scatter_vals_kernel<<<(E + 255) / 256, 256, 0, stream>>>(rc, row_start4, cursor,
                                                             values, col_sorted, vals_h, E);
    dim3 grid(n_quads, (batch + 255) / 256);
    spmm_fb_kernel<<<grid, 256, 0, stream>>>(row_start4, col_sorted, vals_h, x,
                                             biases, out, n_nodes, batch, size);
  } else {
    size_t total = (size_t)batch * size;
    bias_init_kernel<<<(total + 255) / 256, 256, 0, stream>>>(out, biases, batch, size);
    atomic_spmm_kernel<<<nnz, 256, 0, stream>>>(indices, values, x, out, nnz, batch, size);
  }
}